// Round 1
// baseline (2326.348 us; speedup 1.0000x reference)
//
#include <hip/hip_runtime.h>

#define N_NODES 253952
#define N_EDGES 4000000
#define N_GRAPHS 4096
#define NEG_SLOPE 0.01f

__device__ __forceinline__ float lrelu(float v) {
    return v > 0.0f ? v : v * NEG_SLOPE;
}

// agg[dst, :] += x[src, :] * ew   — one thread per (edge, feature)
template <int W>
__global__ void scatter_kernel(const float* __restrict__ x,
                               const int* __restrict__ src,
                               const int* __restrict__ dst,
                               const float* __restrict__ ew,
                               float* __restrict__ agg) {
    unsigned tid = blockIdx.x * blockDim.x + threadIdx.x;
    if (tid >= (unsigned)N_EDGES * W) return;
    unsigned e = tid / W;
    unsigned j = tid - e * W;
    int s = src[e];
    int d = dst[e];
    float w = ew[e];
    float v = x[(long long)s * W + j] * w;
    atomicAdd(&agg[(long long)d * W + j], v);
}

// h[i, j] = lrelu( sum_k agg[i,k] * W[k,j] + b[j] )   (optionally lrelu twice)
template <int WIN, int WOUT, bool DOUBLE_LRELU>
__global__ void linear_lrelu_kernel(const float* __restrict__ agg,
                                    const float* __restrict__ Wg,
                                    const float* __restrict__ bg,
                                    float* __restrict__ h) {
    __shared__ float Ws[WIN * WOUT];
    __shared__ float bs[WOUT];
    for (int i = threadIdx.x; i < WIN * WOUT; i += blockDim.x) Ws[i] = Wg[i];
    for (int i = threadIdx.x; i < WOUT; i += blockDim.x) bs[i] = bg[i];
    __syncthreads();
    int tid = blockIdx.x * blockDim.x + threadIdx.x;
    if (tid >= N_NODES * WOUT) return;
    int node = tid / WOUT;
    int j = tid - node * WOUT;
    const float* arow = agg + (long long)node * WIN;
    float acc = bs[j];
#pragma unroll
    for (int k = 0; k < WIN; ++k) acc += arow[k] * Ws[k * WOUT + j];
    acc = lrelu(acc);
    if (DOUBLE_LRELU) acc = lrelu(acc);
    h[tid] = acc;
}

// One block per graph; batch[] is sorted, so binary-search the node range.
__global__ void pool_kernel(const float* __restrict__ h,
                            const int* __restrict__ batch,
                            float* __restrict__ pooled) {
    int g = blockIdx.x;
    __shared__ int s_start, s_end;
    if (threadIdx.x == 0) {
        int lo = 0, hi = N_NODES;
        while (lo < hi) { int m = (lo + hi) >> 1; if (batch[m] < g) lo = m + 1; else hi = m; }
        s_start = lo;
        lo = 0; hi = N_NODES;
        while (lo < hi) { int m = (lo + hi) >> 1; if (batch[m] < g + 1) lo = m + 1; else hi = m; }
        s_end = lo;
    }
    __syncthreads();
    int j = threadIdx.x;
    if (j < 50) {
        float acc = 0.0f;
        for (int i = s_start; i < s_end; ++i) acc += h[(long long)i * 50 + j];
        pooled[g * 50 + j] = acc;
    }
}

// Final 3-layer MLP: one thread per graph, all weights in LDS.
__global__ void mlp_kernel(const float* __restrict__ pooled,
                           const float* __restrict__ Wf1, const float* __restrict__ bf1,
                           const float* __restrict__ Wf2, const float* __restrict__ bf2,
                           const float* __restrict__ Wf3, const float* __restrict__ bf3,
                           float* __restrict__ out) {
    __shared__ float W1s[50 * 30], b1s[30];
    __shared__ float W2s[30 * 20], b2s[20];
    __shared__ float W3s[20 * 2], b3s[2];
    for (int i = threadIdx.x; i < 50 * 30; i += blockDim.x) W1s[i] = Wf1[i];
    for (int i = threadIdx.x; i < 30; i += blockDim.x) b1s[i] = bf1[i];
    for (int i = threadIdx.x; i < 30 * 20; i += blockDim.x) W2s[i] = Wf2[i];
    for (int i = threadIdx.x; i < 20; i += blockDim.x) b2s[i] = bf2[i];
    for (int i = threadIdx.x; i < 20 * 2; i += blockDim.x) W3s[i] = Wf3[i];
    for (int i = threadIdx.x; i < 2; i += blockDim.x) b3s[i] = bf3[i];
    __syncthreads();
    int g = blockIdx.x * blockDim.x + threadIdx.x;
    if (g >= N_GRAPHS) return;
    float in[50];
#pragma unroll
    for (int k = 0; k < 50; ++k) in[k] = pooled[g * 50 + k];
    float t1[30];
#pragma unroll
    for (int j = 0; j < 30; ++j) {
        float a = b1s[j];
#pragma unroll
        for (int k = 0; k < 50; ++k) a += in[k] * W1s[k * 30 + j];
        t1[j] = lrelu(a);
    }
    float t2[20];
#pragma unroll
    for (int j = 0; j < 20; ++j) {
        float a = b2s[j];
#pragma unroll
        for (int k = 0; k < 30; ++k) a += t1[k] * W2s[k * 20 + j];
        t2[j] = lrelu(a);
    }
#pragma unroll
    for (int j = 0; j < 2; ++j) {
        float a = b3s[j];
#pragma unroll
        for (int k = 0; k < 20; ++k) a += t2[k] * W3s[k * 2 + j];
        out[g * 2 + j] = lrelu(a);
    }
}

extern "C" void kernel_launch(void* const* d_in, const int* in_sizes, int n_in,
                              void* d_out, int out_size, void* d_ws, size_t ws_size,
                              hipStream_t stream) {
    const float* x     = (const float*)d_in[0];
    const int*   ei    = (const int*)d_in[1];
    const float* ew    = (const float*)d_in[2];
    const int*   batch = (const int*)d_in[3];
    const float* W1 = (const float*)d_in[4];
    const float* b1 = (const float*)d_in[5];
    const float* W2 = (const float*)d_in[6];
    const float* b2 = (const float*)d_in[7];
    const float* W3 = (const float*)d_in[8];
    const float* b3 = (const float*)d_in[9];
    const float* W4 = (const float*)d_in[10];
    const float* b4 = (const float*)d_in[11];
    const float* Wf1 = (const float*)d_in[12];
    const float* bf1 = (const float*)d_in[13];
    const float* Wf2 = (const float*)d_in[14];
    const float* bf2 = (const float*)d_in[15];
    const float* Wf3 = (const float*)d_in[16];
    const float* bf3 = (const float*)d_in[17];

    const int* src = ei;            // edge_index[0]
    const int* dst = ei + N_EDGES;  // edge_index[1]
    float* out = (float*)d_out;

    // Workspace layout (all fp32):
    //   agg  : N*64   (reused per layer, zeroed each time)
    //   bufA : N*64   (h1 [N,16], later h3 [N,64])
    //   bufB : N*64   (h2 [N,32], later h4 [N,50])
    //   pooled: 4096*50
    const size_t node64 = (size_t)N_NODES * 64;
    float* agg    = (float*)d_ws;
    float* bufA   = agg + node64;
    float* bufB   = bufA + node64;
    float* pooled = bufB + node64;

    const int BS = 256;
    auto blocks = [](long long total, int bs) { return (unsigned)((total + bs - 1) / bs); };

    // Layer 1: scatter x (w=6) -> agg ; h1 = lrelu(agg @ W1 + b1)  [N,16]
    hipMemsetAsync(agg, 0, (size_t)N_NODES * 6 * sizeof(float), stream);
    scatter_kernel<6><<<blocks((long long)N_EDGES * 6, BS), BS, 0, stream>>>(x, src, dst, ew, agg);
    linear_lrelu_kernel<6, 16, false><<<blocks((long long)N_NODES * 16, BS), BS, 0, stream>>>(agg, W1, b1, bufA);

    // Layer 2: scatter h1 (w=16) -> agg ; h2 = lrelu(agg @ W2 + b2)  [N,32]
    hipMemsetAsync(agg, 0, (size_t)N_NODES * 16 * sizeof(float), stream);
    scatter_kernel<16><<<blocks((long long)N_EDGES * 16, BS), BS, 0, stream>>>(bufA, src, dst, ew, agg);
    linear_lrelu_kernel<16, 32, false><<<blocks((long long)N_NODES * 32, BS), BS, 0, stream>>>(agg, W2, b2, bufB);

    // Layer 3: scatter h2 (w=32) -> agg ; h3 = lrelu(agg @ W3 + b3)  [N,64]
    hipMemsetAsync(agg, 0, (size_t)N_NODES * 32 * sizeof(float), stream);
    scatter_kernel<32><<<blocks((long long)N_EDGES * 32, BS), BS, 0, stream>>>(bufB, src, dst, ew, agg);
    linear_lrelu_kernel<32, 64, false><<<blocks((long long)N_NODES * 64, BS), BS, 0, stream>>>(agg, W3, b3, bufA);

    // Layer 4: scatter h3 (w=64) -> agg ; h4 = lrelu(lrelu(agg @ W4 + b4))  [N,50]
    hipMemsetAsync(agg, 0, (size_t)N_NODES * 64 * sizeof(float), stream);
    scatter_kernel<64><<<blocks((long long)N_EDGES * 64, BS), BS, 0, stream>>>(bufA, src, dst, ew, agg);
    linear_lrelu_kernel<64, 50, true><<<blocks((long long)N_NODES * 50, BS), BS, 0, stream>>>(agg, W4, b4, bufB);

    // Pool: pooled[g,:] = sum over nodes of graph g (batch sorted -> binary search)
    pool_kernel<<<N_GRAPHS, 64, 0, stream>>>(bufB, batch, pooled);

    // MLP: [4096,50] -> 30 -> 20 -> 2, lrelu after each
    mlp_kernel<<<(N_GRAPHS + 255) / 256, 256, 0, stream>>>(pooled, Wf1, bf1, Wf2, bf2, Wf3, bf3, out);
}

// Round 2
// 1782.428 us; speedup vs baseline: 1.3052x; 1.3052x over previous
//
#include <hip/hip_runtime.h>

#define N_NODES 253952   // = 992 * 256 exactly
#define N_EDGES 4000000
#define N_GRAPHS 4096
#define NEG_SLOPE 0.01f

__device__ __forceinline__ float lrelu(float v) {
    return v > 0.0f ? v : v * NEG_SLOPE;
}

// ---------------- CSR build ----------------

__global__ void hist_kernel(const int* __restrict__ dst, int* __restrict__ deg) {
    int e = blockIdx.x * blockDim.x + threadIdx.x;
    if (e < N_EDGES) atomicAdd(&deg[dst[e]], 1);
}

// Per-block exclusive scan of deg -> row_start (block-local), block totals -> partials
__global__ void scan1_kernel(const int* __restrict__ deg, int* __restrict__ row_start,
                             int* __restrict__ partials) {
    __shared__ int s[256];
    int i = blockIdx.x * 256 + threadIdx.x;      // N_NODES divisible by 256
    int v = deg[i];
    s[threadIdx.x] = v;
    __syncthreads();
    for (int off = 1; off < 256; off <<= 1) {
        int t = (threadIdx.x >= off) ? s[threadIdx.x - off] : 0;
        __syncthreads();
        s[threadIdx.x] += t;
        __syncthreads();
    }
    row_start[i] = s[threadIdx.x] - v;           // exclusive
    if (threadIdx.x == 255) partials[blockIdx.x] = s[255];
}

// Single-block exclusive scan of partials[n]
__global__ void scan2_kernel(int* __restrict__ partials, int n) {
    __shared__ int s[256];
    __shared__ int carry;
    if (threadIdx.x == 0) carry = 0;
    __syncthreads();
    for (int base = 0; base < n; base += 256) {
        int c = carry;
        __syncthreads();
        int i = base + threadIdx.x;
        int v = (i < n) ? partials[i] : 0;
        s[threadIdx.x] = v;
        __syncthreads();
        for (int off = 1; off < 256; off <<= 1) {
            int t = (threadIdx.x >= off) ? s[threadIdx.x - off] : 0;
            __syncthreads();
            s[threadIdx.x] += t;
            __syncthreads();
        }
        if (i < n) partials[i] = c + s[threadIdx.x] - v;
        __syncthreads();
        if (threadIdx.x == 0) carry = c + s[255];
        __syncthreads();
    }
}

// Add block offsets; also init cursor = row_start
__global__ void scan3_kernel(int* __restrict__ row_start, const int* __restrict__ partials,
                             int* __restrict__ cursor) {
    int i = blockIdx.x * 256 + threadIdx.x;
    int rs = row_start[i] + partials[blockIdx.x];
    row_start[i] = rs;
    cursor[i] = rs;
}

// Place each edge at its CSR slot. After this, cursor[n] == row_end[n].
__global__ void fill_kernel(const int* __restrict__ src, const int* __restrict__ dst,
                            const float* __restrict__ ew, int* __restrict__ cursor,
                            int2* __restrict__ csr) {
    int e = blockIdx.x * blockDim.x + threadIdx.x;
    if (e >= N_EDGES) return;
    int d = dst[e];
    int pos = atomicAdd(&cursor[d], 1);
    csr[pos] = make_int2(src[e], __float_as_int(ew[e]));
}

// ---------------- Fused GCN layer: gather (CSR) + linear + lrelu ----------------
// LPN lanes per node (LPN >= WIN, LPN divides 64). Each group of LPN lanes
// accumulates one node's aggregated input row in registers (one feature/lane),
// parks it in LDS, then the block applies the WIN->WOUT transform + bias + lrelu.
template <int WIN, int LPN, int WOUT, bool DBL>
__global__ void gcn_layer_kernel(const float* __restrict__ x, const int2* __restrict__ csr,
                                 const int* __restrict__ row_start, const int* __restrict__ row_end,
                                 const float* __restrict__ Wg, const float* __restrict__ bg,
                                 float* __restrict__ h) {
    constexpr int GROUPS = 256 / LPN;
    __shared__ float rows[GROUPS][WIN + 1];   // +1 pad: avoid bank conflicts in phase 2
    int g = threadIdx.x / LPN;
    int j = threadIdx.x % LPN;
    int node = blockIdx.x * GROUPS + g;
    float acc = 0.0f;
    if (node < N_NODES) {
        int start = row_start[node];
        int end = row_end[node];
        for (int e = start; e < end; ++e) {
            int2 rec = csr[e];                       // broadcast across the group
            float w = __int_as_float(rec.y);
            if (j < WIN) acc += x[(size_t)rec.x * WIN + j] * w;
        }
    }
    if (j < WIN) rows[g][j] = acc;
    __syncthreads();
    for (int idx = threadIdx.x; idx < GROUPS * WOUT; idx += 256) {
        int g2 = idx / WOUT;
        int j2 = idx - g2 * WOUT;
        int node2 = blockIdx.x * GROUPS + g2;
        if (node2 >= N_NODES) break;
        float a = bg[j2];
#pragma unroll
        for (int k = 0; k < WIN; ++k) a += rows[g2][k] * Wg[k * WOUT + j2];
        a = lrelu(a);
        if (DBL) a = lrelu(a);
        h[(size_t)node2 * WOUT + j2] = a;
    }
}

// ---------------- Pool (batch is sorted -> binary search range) ----------------
__global__ void pool_kernel(const float* __restrict__ h,
                            const int* __restrict__ batch,
                            float* __restrict__ pooled) {
    int g = blockIdx.x;
    __shared__ int s_start, s_end;
    if (threadIdx.x == 0) {
        int lo = 0, hi = N_NODES;
        while (lo < hi) { int m = (lo + hi) >> 1; if (batch[m] < g) lo = m + 1; else hi = m; }
        s_start = lo;
        lo = 0; hi = N_NODES;
        while (lo < hi) { int m = (lo + hi) >> 1; if (batch[m] < g + 1) lo = m + 1; else hi = m; }
        s_end = lo;
    }
    __syncthreads();
    int j = threadIdx.x;
    if (j < 50) {
        float acc = 0.0f;
        for (int i = s_start; i < s_end; ++i) acc += h[(size_t)i * 50 + j];
        pooled[g * 50 + j] = acc;
    }
}

// ---------------- Final MLP ----------------
__global__ void mlp_kernel(const float* __restrict__ pooled,
                           const float* __restrict__ Wf1, const float* __restrict__ bf1,
                           const float* __restrict__ Wf2, const float* __restrict__ bf2,
                           const float* __restrict__ Wf3, const float* __restrict__ bf3,
                           float* __restrict__ out) {
    __shared__ float W1s[50 * 30], b1s[30];
    __shared__ float W2s[30 * 20], b2s[20];
    __shared__ float W3s[20 * 2], b3s[2];
    for (int i = threadIdx.x; i < 50 * 30; i += blockDim.x) W1s[i] = Wf1[i];
    for (int i = threadIdx.x; i < 30; i += blockDim.x) b1s[i] = bf1[i];
    for (int i = threadIdx.x; i < 30 * 20; i += blockDim.x) W2s[i] = Wf2[i];
    for (int i = threadIdx.x; i < 20; i += blockDim.x) b2s[i] = bf2[i];
    for (int i = threadIdx.x; i < 20 * 2; i += blockDim.x) W3s[i] = Wf3[i];
    for (int i = threadIdx.x; i < 2; i += blockDim.x) b3s[i] = bf3[i];
    __syncthreads();
    int g = blockIdx.x * blockDim.x + threadIdx.x;
    if (g >= N_GRAPHS) return;
    float in[50];
#pragma unroll
    for (int k = 0; k < 50; ++k) in[k] = pooled[g * 50 + k];
    float t1[30];
#pragma unroll
    for (int j = 0; j < 30; ++j) {
        float a = b1s[j];
#pragma unroll
        for (int k = 0; k < 50; ++k) a += in[k] * W1s[k * 30 + j];
        t1[j] = lrelu(a);
    }
    float t2[20];
#pragma unroll
    for (int j = 0; j < 20; ++j) {
        float a = b2s[j];
#pragma unroll
        for (int k = 0; k < 30; ++k) a += t1[k] * W2s[k * 20 + j];
        t2[j] = lrelu(a);
    }
#pragma unroll
    for (int j = 0; j < 2; ++j) {
        float a = b3s[j];
#pragma unroll
        for (int k = 0; k < 20; ++k) a += t2[k] * W3s[k * 2 + j];
        out[g * 2 + j] = lrelu(a);
    }
}

extern "C" void kernel_launch(void* const* d_in, const int* in_sizes, int n_in,
                              void* d_out, int out_size, void* d_ws, size_t ws_size,
                              hipStream_t stream) {
    const float* x     = (const float*)d_in[0];
    const int*   ei    = (const int*)d_in[1];
    const float* ew    = (const float*)d_in[2];
    const int*   batch = (const int*)d_in[3];
    const float* W1 = (const float*)d_in[4];
    const float* b1 = (const float*)d_in[5];
    const float* W2 = (const float*)d_in[6];
    const float* b2 = (const float*)d_in[7];
    const float* W3 = (const float*)d_in[8];
    const float* b3 = (const float*)d_in[9];
    const float* W4 = (const float*)d_in[10];
    const float* b4 = (const float*)d_in[11];
    const float* Wf1 = (const float*)d_in[12];
    const float* bf1 = (const float*)d_in[13];
    const float* Wf2 = (const float*)d_in[14];
    const float* bf2 = (const float*)d_in[15];
    const float* Wf3 = (const float*)d_in[16];
    const float* bf3 = (const float*)d_in[17];

    const int* src = ei;            // edge_index[0]
    const int* dst = ei + N_EDGES;  // edge_index[1]
    float* out = (float*)d_out;

    // Workspace layout (4-byte words). csr first for 8B alignment.
    //   csr      : 2*E ints (int2 per edge)          = 8,000,000 words
    //   bufA     : N*64 floats                        (h1[16] then h3[64])
    //   bufB     : N*50 floats                        (h2[32] then h4[50])
    //   deg      : N ints
    //   row_start: N ints
    //   cursor   : N ints (== row_end after fill)
    //   partials : 1024 ints
    //   pooled   : 4096*50 floats
    char* wsp = (char*)d_ws;
    int2*  csr       = (int2*)wsp;                 wsp += (size_t)N_EDGES * 8;
    float* bufA      = (float*)wsp;                wsp += (size_t)N_NODES * 64 * 4;
    float* bufB      = (float*)wsp;                wsp += (size_t)N_NODES * 50 * 4;
    int*   deg       = (int*)wsp;                  wsp += (size_t)N_NODES * 4;
    int*   row_start = (int*)wsp;                  wsp += (size_t)N_NODES * 4;
    int*   cursor    = (int*)wsp;                  wsp += (size_t)N_NODES * 4;
    int*   partials  = (int*)wsp;                  wsp += 1024 * 4;
    float* pooled    = (float*)wsp;

    const int BS = 256;
    const int NBLK = N_NODES / 256;                // 992, exact
    const int EBLK = (N_EDGES + BS - 1) / BS;      // 15625

    // ---- CSR build ----
    hipMemsetAsync(deg, 0, (size_t)N_NODES * 4, stream);
    hist_kernel<<<EBLK, BS, 0, stream>>>(dst, deg);
    scan1_kernel<<<NBLK, BS, 0, stream>>>(deg, row_start, partials);
    scan2_kernel<<<1, BS, 0, stream>>>(partials, NBLK);
    scan3_kernel<<<NBLK, BS, 0, stream>>>(row_start, partials, cursor);
    fill_kernel<<<EBLK, BS, 0, stream>>>(src, dst, ew, cursor, csr);

    // ---- 4 fused GCN layers (gather + linear + lrelu) ----
    // L1: x[N,6]  -> h1[N,16]   (LPN=8, 32 nodes/block)
    gcn_layer_kernel<6, 8, 16, false><<<(N_NODES + 31) / 32, BS, 0, stream>>>(
        x, csr, row_start, cursor, W1, b1, bufA);
    // L2: h1[N,16] -> h2[N,32]  (16 nodes/block)
    gcn_layer_kernel<16, 16, 32, false><<<(N_NODES + 15) / 16, BS, 0, stream>>>(
        bufA, csr, row_start, cursor, W2, b2, bufB);
    // L3: h2[N,32] -> h3[N,64]  (8 nodes/block)
    gcn_layer_kernel<32, 32, 64, false><<<(N_NODES + 7) / 8, BS, 0, stream>>>(
        bufB, csr, row_start, cursor, W3, b3, bufA);
    // L4: h3[N,64] -> h4[N,50]  (4 nodes/block, double lrelu)
    gcn_layer_kernel<64, 64, 50, true><<<(N_NODES + 3) / 4, BS, 0, stream>>>(
        bufA, csr, row_start, cursor, W4, b4, bufB);

    // ---- Pool + MLP ----
    pool_kernel<<<N_GRAPHS, 64, 0, stream>>>(bufB, batch, pooled);
    mlp_kernel<<<(N_GRAPHS + 255) / 256, 256, 0, stream>>>(pooled, Wf1, bf1, Wf2, bf2, Wf3, bf3, out);
}

// Round 3
// 1173.198 us; speedup vs baseline: 1.9829x; 1.5193x over previous
//
#include <hip/hip_runtime.h>

#define N_NODES 253952   // = 992 * 256 exactly
#define N_EDGES 4000000
#define N_GRAPHS 4096
#define NEG_SLOPE 0.01f

__device__ __forceinline__ float lrelu(float v) {
    return v > 0.0f ? v : v * NEG_SLOPE;
}

__device__ __forceinline__ void fma4(float4& a, const float4 v, const float w) {
    a.x += v.x * w; a.y += v.y * w; a.z += v.z * w; a.w += v.w * w;
}

// ---------------- CSR build ----------------

__global__ void hist_kernel(const int* __restrict__ dst, int* __restrict__ deg) {
    int e = blockIdx.x * blockDim.x + threadIdx.x;
    if (e < N_EDGES) atomicAdd(&deg[dst[e]], 1);
}

__global__ void scan1_kernel(const int* __restrict__ deg, int* __restrict__ row_start,
                             int* __restrict__ partials) {
    __shared__ int s[256];
    int i = blockIdx.x * 256 + threadIdx.x;
    int v = deg[i];
    s[threadIdx.x] = v;
    __syncthreads();
    for (int off = 1; off < 256; off <<= 1) {
        int t = (threadIdx.x >= off) ? s[threadIdx.x - off] : 0;
        __syncthreads();
        s[threadIdx.x] += t;
        __syncthreads();
    }
    row_start[i] = s[threadIdx.x] - v;
    if (threadIdx.x == 255) partials[blockIdx.x] = s[255];
}

__global__ void scan2_kernel(int* __restrict__ partials, int n) {
    __shared__ int s[256];
    __shared__ int carry;
    if (threadIdx.x == 0) carry = 0;
    __syncthreads();
    for (int base = 0; base < n; base += 256) {
        int c = carry;
        __syncthreads();
        int i = base + threadIdx.x;
        int v = (i < n) ? partials[i] : 0;
        s[threadIdx.x] = v;
        __syncthreads();
        for (int off = 1; off < 256; off <<= 1) {
            int t = (threadIdx.x >= off) ? s[threadIdx.x - off] : 0;
            __syncthreads();
            s[threadIdx.x] += t;
            __syncthreads();
        }
        if (i < n) partials[i] = c + s[threadIdx.x] - v;
        __syncthreads();
        if (threadIdx.x == 0) carry = c + s[255];
        __syncthreads();
    }
}

__global__ void scan3_kernel(int* __restrict__ row_start, const int* __restrict__ partials,
                             int* __restrict__ cursor) {
    int i = blockIdx.x * 256 + threadIdx.x;
    int rs = row_start[i] + partials[blockIdx.x];
    row_start[i] = rs;
    cursor[i] = rs;
}

__global__ void fill_kernel(const int* __restrict__ src, const int* __restrict__ dst,
                            const float* __restrict__ ew, int* __restrict__ cursor,
                            int2* __restrict__ csr) {
    int e = blockIdx.x * blockDim.x + threadIdx.x;
    if (e >= N_EDGES) return;
    int d = dst[e];
    int pos = atomicAdd(&cursor[d], 1);
    csr[pos] = make_int2(src[e], __float_as_int(ew[e]));
}

// Pad x [N,6] -> xp [N,8] (zeros in 6,7) so gathers are float4-aligned.
__global__ void pad_x_kernel(const float* __restrict__ x, float* __restrict__ xp) {
    int i = blockIdx.x * 256 + threadIdx.x;
    if (i >= N_NODES * 8) return;
    int n = i >> 3, j = i & 7;
    xp[i] = (j < 6) ? x[n * 6 + j] : 0.0f;
}

// ---------------- Fused GCN layer: CSR gather (float4/lane) + linear + lrelu ----
// WPAD: padded input row width (floats, mult of 4). LPN = WPAD/4 lanes per node,
// each lane accumulates a float4 of features. 256/LPN nodes per block.
// Manual 4x edge unroll -> ~4 gathers in flight per node group.
template <int WPAD, int WIN, int WOUT, bool DBL>
__global__ void gcn_layer_kernel(const float* __restrict__ x, const int2* __restrict__ csr,
                                 const int* __restrict__ row_start, const int* __restrict__ row_end,
                                 const float* __restrict__ Wg, const float* __restrict__ bg,
                                 float* __restrict__ h) {
    constexpr int LPN = WPAD / 4;
    constexpr int GROUPS = 256 / LPN;
    __shared__ float rows[GROUPS][WPAD];
    int g = threadIdx.x / LPN;
    int j = threadIdx.x % LPN;
    int node = blockIdx.x * GROUPS + g;   // N_NODES % GROUPS == 0: no guard needed
    float4 acc = make_float4(0.f, 0.f, 0.f, 0.f);
    int e = row_start[node];
    int end = row_end[node];
    for (; e + 4 <= end; e += 4) {
        int2 r0 = csr[e];
        int2 r1 = csr[e + 1];
        int2 r2 = csr[e + 2];
        int2 r3 = csr[e + 3];
        float4 v0 = ((const float4*)(x + (size_t)r0.x * WPAD))[j];
        float4 v1 = ((const float4*)(x + (size_t)r1.x * WPAD))[j];
        float4 v2 = ((const float4*)(x + (size_t)r2.x * WPAD))[j];
        float4 v3 = ((const float4*)(x + (size_t)r3.x * WPAD))[j];
        fma4(acc, v0, __int_as_float(r0.y));
        fma4(acc, v1, __int_as_float(r1.y));
        fma4(acc, v2, __int_as_float(r2.y));
        fma4(acc, v3, __int_as_float(r3.y));
    }
    for (; e < end; ++e) {
        int2 r = csr[e];
        float4 v = ((const float4*)(x + (size_t)r.x * WPAD))[j];
        fma4(acc, v, __int_as_float(r.y));
    }
    ((float4*)rows[g])[j] = acc;
    __syncthreads();
    for (int idx = threadIdx.x; idx < GROUPS * WOUT; idx += 256) {
        int g2 = idx / WOUT;
        int j2 = idx - g2 * WOUT;
        int node2 = blockIdx.x * GROUPS + g2;
        float a = bg[j2];
#pragma unroll
        for (int k = 0; k < WIN; ++k) a += rows[g2][k] * Wg[k * WOUT + j2];
        a = lrelu(a);
        if (DBL) a = lrelu(a);
        h[(size_t)node2 * WOUT + j2] = a;
    }
}

// ---------------- Pool (batch sorted -> binary search range) ----------------
__global__ void pool_kernel(const float* __restrict__ h,
                            const int* __restrict__ batch,
                            float* __restrict__ pooled) {
    int g = blockIdx.x;
    __shared__ int s_start, s_end;
    if (threadIdx.x == 0) {
        int lo = 0, hi = N_NODES;
        while (lo < hi) { int m = (lo + hi) >> 1; if (batch[m] < g) lo = m + 1; else hi = m; }
        s_start = lo;
        lo = 0; hi = N_NODES;
        while (lo < hi) { int m = (lo + hi) >> 1; if (batch[m] < g + 1) lo = m + 1; else hi = m; }
        s_end = lo;
    }
    __syncthreads();
    int j = threadIdx.x;
    if (j < 50) {
        float acc = 0.0f;
        for (int i = s_start; i < s_end; ++i) acc += h[(size_t)i * 50 + j];
        pooled[g * 50 + j] = acc;
    }
}

// ---------------- Final MLP ----------------
__global__ void mlp_kernel(const float* __restrict__ pooled,
                           const float* __restrict__ Wf1, const float* __restrict__ bf1,
                           const float* __restrict__ Wf2, const float* __restrict__ bf2,
                           const float* __restrict__ Wf3, const float* __restrict__ bf3,
                           float* __restrict__ out) {
    __shared__ float W1s[50 * 30], b1s[30];
    __shared__ float W2s[30 * 20], b2s[20];
    __shared__ float W3s[20 * 2], b3s[2];
    for (int i = threadIdx.x; i < 50 * 30; i += blockDim.x) W1s[i] = Wf1[i];
    for (int i = threadIdx.x; i < 30; i += blockDim.x) b1s[i] = bf1[i];
    for (int i = threadIdx.x; i < 30 * 20; i += blockDim.x) W2s[i] = Wf2[i];
    for (int i = threadIdx.x; i < 20; i += blockDim.x) b2s[i] = bf2[i];
    for (int i = threadIdx.x; i < 20 * 2; i += blockDim.x) W3s[i] = Wf3[i];
    for (int i = threadIdx.x; i < 2; i += blockDim.x) b3s[i] = bf3[i];
    __syncthreads();
    int g = blockIdx.x * blockDim.x + threadIdx.x;
    if (g >= N_GRAPHS) return;
    float in[50];
#pragma unroll
    for (int k = 0; k < 50; ++k) in[k] = pooled[g * 50 + k];
    float t1[30];
#pragma unroll
    for (int j = 0; j < 30; ++j) {
        float a = b1s[j];
#pragma unroll
        for (int k = 0; k < 50; ++k) a += in[k] * W1s[k * 30 + j];
        t1[j] = lrelu(a);
    }
    float t2[20];
#pragma unroll
    for (int j = 0; j < 20; ++j) {
        float a = b2s[j];
#pragma unroll
        for (int k = 0; k < 30; ++k) a += t1[k] * W2s[k * 20 + j];
        t2[j] = lrelu(a);
    }
#pragma unroll
    for (int j = 0; j < 2; ++j) {
        float a = b3s[j];
#pragma unroll
        for (int k = 0; k < 20; ++k) a += t2[k] * W3s[k * 2 + j];
        out[g * 2 + j] = lrelu(a);
    }
}

extern "C" void kernel_launch(void* const* d_in, const int* in_sizes, int n_in,
                              void* d_out, int out_size, void* d_ws, size_t ws_size,
                              hipStream_t stream) {
    const float* x     = (const float*)d_in[0];
    const int*   ei    = (const int*)d_in[1];
    const float* ew    = (const float*)d_in[2];
    const int*   batch = (const int*)d_in[3];
    const float* W1 = (const float*)d_in[4];
    const float* b1 = (const float*)d_in[5];
    const float* W2 = (const float*)d_in[6];
    const float* b2 = (const float*)d_in[7];
    const float* W3 = (const float*)d_in[8];
    const float* b3 = (const float*)d_in[9];
    const float* W4 = (const float*)d_in[10];
    const float* b4 = (const float*)d_in[11];
    const float* Wf1 = (const float*)d_in[12];
    const float* bf1 = (const float*)d_in[13];
    const float* Wf2 = (const float*)d_in[14];
    const float* bf2 = (const float*)d_in[15];
    const float* Wf3 = (const float*)d_in[16];
    const float* bf3 = (const float*)d_in[17];

    const int* src = ei;            // edge_index[0]
    const int* dst = ei + N_EDGES;  // edge_index[1]
    float* out = (float*)d_out;

    // Workspace layout (bytes):
    //   csr      : E int2            (32 MB)
    //   bufA     : N*64 f32          (h1[16], h3[64])
    //   bufB     : N*50 f32          (xp[N,8] first, then h2[32], h4[50])
    //   deg/row_start/cursor : N int each
    //   partials : 1024 int
    //   pooled   : 4096*50 f32
    char* wsp = (char*)d_ws;
    int2*  csr       = (int2*)wsp;                 wsp += (size_t)N_EDGES * 8;
    float* bufA      = (float*)wsp;                wsp += (size_t)N_NODES * 64 * 4;
    float* bufB      = (float*)wsp;                wsp += (size_t)N_NODES * 50 * 4;
    int*   deg       = (int*)wsp;                  wsp += (size_t)N_NODES * 4;
    int*   row_start = (int*)wsp;                  wsp += (size_t)N_NODES * 4;
    int*   cursor    = (int*)wsp;                  wsp += (size_t)N_NODES * 4;
    int*   partials  = (int*)wsp;                  wsp += 1024 * 4;
    float* pooled    = (float*)wsp;

    float* xp = bufB;   // [N,8] padded x; bufB not needed until layer-2 output

    const int BS = 256;
    const int NBLK = N_NODES / 256;                // 992
    const int EBLK = (N_EDGES + BS - 1) / BS;

    // ---- CSR build + x pad ----
    hipMemsetAsync(deg, 0, (size_t)N_NODES * 4, stream);
    hist_kernel<<<EBLK, BS, 0, stream>>>(dst, deg);
    pad_x_kernel<<<(N_NODES * 8 + 255) / 256, BS, 0, stream>>>(x, xp);
    scan1_kernel<<<NBLK, BS, 0, stream>>>(deg, row_start, partials);
    scan2_kernel<<<1, BS, 0, stream>>>(partials, NBLK);
    scan3_kernel<<<NBLK, BS, 0, stream>>>(row_start, partials, cursor);
    fill_kernel<<<EBLK, BS, 0, stream>>>(src, dst, ew, cursor, csr);

    // ---- 4 fused GCN layers ----
    // L1: xp[N,8(6)] -> h1[N,16]   LPN=2, 128 nodes/block
    gcn_layer_kernel<8, 6, 16, false><<<N_NODES / 128, BS, 0, stream>>>(
        xp, csr, row_start, cursor, W1, b1, bufA);
    // L2: h1[N,16] -> h2[N,32]     LPN=4, 64 nodes/block
    gcn_layer_kernel<16, 16, 32, false><<<N_NODES / 64, BS, 0, stream>>>(
        bufA, csr, row_start, cursor, W2, b2, bufB);
    // L3: h2[N,32] -> h3[N,64]     LPN=8, 32 nodes/block
    gcn_layer_kernel<32, 32, 64, false><<<N_NODES / 32, BS, 0, stream>>>(
        bufB, csr, row_start, cursor, W3, b3, bufA);
    // L4: h3[N,64] -> h4[N,50]     LPN=16, 16 nodes/block, double lrelu
    gcn_layer_kernel<64, 64, 50, true><<<N_NODES / 16, BS, 0, stream>>>(
        bufA, csr, row_start, cursor, W4, b4, bufB);

    // ---- Pool + MLP ----
    pool_kernel<<<N_GRAPHS, 64, 0, stream>>>(bufB, batch, pooled);
    mlp_kernel<<<(N_GRAPHS + 255) / 256, 256, 0, stream>>>(pooled, Wf1, bf1, Wf2, bf2, Wf3, bf3, out);
}

// Round 4
// 829.271 us; speedup vs baseline: 2.8053x; 1.4147x over previous
//
#include <hip/hip_runtime.h>

#define N_NODES 253952   // = 992 * 256 = 248 * 1024 exactly
#define N_EDGES 4000000
#define N_GRAPHS 4096
#define NEG_SLOPE 0.01f

#define NB   248          // buckets (1024 nodes each)
#define CAP  20480        // staging capacity per bucket (mean 16129, sigma ~127)
#define EPB  4096         // edges per partA block

__device__ __forceinline__ float lrelu(float v) {
    return v > 0.0f ? v : v * NEG_SLOPE;
}

__device__ __forceinline__ void fma4(float4& a, const float4 v, const float w) {
    a.x += v.x * w; a.y += v.y * w; a.z += v.z * w; a.w += v.w * w;
}

// ---------------- CSR build, pass A: bucket partition ----------------
// Record: x = src | (dst&1023)<<18  (src < 2^18), y = bits(weight)
__global__ void partA_kernel(const int* __restrict__ src, const int* __restrict__ dst,
                             const float* __restrict__ ew,
                             int* __restrict__ bucket_cnt, int2* __restrict__ staging) {
    __shared__ int cnt[NB], base[NB], cur[NB];
    for (int i = threadIdx.x; i < NB; i += 256) cnt[i] = 0;
    __syncthreads();
    const int e0 = blockIdx.x * EPB;
    int s[16], d[16]; float w[16];
#pragma unroll
    for (int k = 0; k < 16; ++k) {
        int e = e0 + k * 256 + threadIdx.x;
        if (e < N_EDGES) { s[k] = src[e]; d[k] = dst[e]; w[k] = ew[e]; }
        else d[k] = -1;
    }
#pragma unroll
    for (int k = 0; k < 16; ++k)
        if (d[k] >= 0) atomicAdd(&cnt[d[k] >> 10], 1);
    __syncthreads();
    for (int i = threadIdx.x; i < NB; i += 256) {
        int c = cnt[i];
        base[i] = (c > 0) ? atomicAdd(&bucket_cnt[i], c) : 0;
        cur[i] = 0;
    }
    __syncthreads();
#pragma unroll
    for (int k = 0; k < 16; ++k) {
        if (d[k] >= 0) {
            int b = d[k] >> 10;
            int off = atomicAdd(&cur[b], 1);
            staging[(size_t)b * CAP + base[b] + off] =
                make_int2(s[k] | ((d[k] & 1023) << 18), __float_as_int(w[k]));
        }
    }
}

// ---------------- bucket base scan (single block) ----------------
__global__ void bucket_scan_kernel(const int* __restrict__ bucket_cnt,
                                   int* __restrict__ bucket_base,
                                   int* __restrict__ row_start) {
    __shared__ int s[256];
    int v = (threadIdx.x < NB) ? bucket_cnt[threadIdx.x] : 0;
    s[threadIdx.x] = v;
    __syncthreads();
    for (int off = 1; off < 256; off <<= 1) {
        int t = (threadIdx.x >= off) ? s[threadIdx.x - off] : 0;
        __syncthreads();
        s[threadIdx.x] += t;
        __syncthreads();
    }
    if (threadIdx.x < NB) bucket_base[threadIdx.x] = s[threadIdx.x] - v;
    if (threadIdx.x == 0) row_start[N_NODES] = N_EDGES;   // sentinel
}

// ---------------- CSR build, pass B: per-bucket counting sort ----------------
// One block per bucket. Derives per-node degrees (LDS hist), scans them,
// emits row_start, then scatters records into the final CSR (L2-window writes).
__global__ void partB_kernel(const int2* __restrict__ staging,
                             const int* __restrict__ bucket_cnt,
                             const int* __restrict__ bucket_base,
                             int* __restrict__ row_start, int2* __restrict__ csr) {
    __shared__ int hist[1024];
    __shared__ int scan_s[256];
    const int b = blockIdx.x;
    const int cnt = bucket_cnt[b];
    const int bbase = bucket_base[b];
    const int2* rec = staging + (size_t)b * CAP;
    for (int i = threadIdx.x; i < 1024; i += 256) hist[i] = 0;
    __syncthreads();
    for (int i = threadIdx.x; i < cnt; i += 256)
        atomicAdd(&hist[rec[i].x >> 18], 1);
    __syncthreads();
    const int t = threadIdx.x;
    int h0 = hist[4 * t], h1 = hist[4 * t + 1], h2 = hist[4 * t + 2], h3 = hist[4 * t + 3];
    int sum = h0 + h1 + h2 + h3;
    scan_s[t] = sum;
    __syncthreads();
    for (int off = 1; off < 256; off <<= 1) {
        int tv = (t >= off) ? scan_s[t - off] : 0;
        __syncthreads();
        scan_s[t] += tv;
        __syncthreads();
    }
    int excl = scan_s[t] - sum;
    int e0 = excl, e1 = excl + h0, e2 = excl + h0 + h1, e3 = excl + h0 + h1 + h2;
    // row_start + reuse hist[] as scatter cursors (each thread owns its 4 slots)
    int node0 = b * 1024 + 4 * t;
    row_start[node0]     = bbase + e0;
    row_start[node0 + 1] = bbase + e1;
    row_start[node0 + 2] = bbase + e2;
    row_start[node0 + 3] = bbase + e3;
    hist[4 * t] = e0; hist[4 * t + 1] = e1; hist[4 * t + 2] = e2; hist[4 * t + 3] = e3;
    __syncthreads();
    for (int i = threadIdx.x; i < cnt; i += 256) {
        int2 r = rec[i];
        int dl = r.x >> 18;
        int pos = bbase + atomicAdd(&hist[dl], 1);
        csr[pos] = make_int2(r.x & 0x3FFFF, r.y);
    }
}

// Pad x [N,6] -> xp [N,8] (zeros in 6,7) so gathers are float4-aligned.
__global__ void pad_x_kernel(const float* __restrict__ x, float* __restrict__ xp) {
    int i = blockIdx.x * 256 + threadIdx.x;
    if (i >= N_NODES * 8) return;
    int n = i >> 3, j = i & 7;
    xp[i] = (j < 6) ? x[n * 6 + j] : 0.0f;
}

// ---------------- Fused GCN layer: CSR gather (float4/lane) + linear + lrelu ----
template <int WPAD, int WIN, int WOUT, bool DBL>
__global__ void gcn_layer_kernel(const float* __restrict__ x, const int2* __restrict__ csr,
                                 const int* __restrict__ row_start, const int* __restrict__ row_end,
                                 const float* __restrict__ Wg, const float* __restrict__ bg,
                                 float* __restrict__ h) {
    constexpr int LPN = WPAD / 4;
    constexpr int GROUPS = 256 / LPN;
    __shared__ float rows[GROUPS][WPAD];
    int g = threadIdx.x / LPN;
    int j = threadIdx.x % LPN;
    int node = blockIdx.x * GROUPS + g;   // N_NODES % GROUPS == 0
    float4 acc = make_float4(0.f, 0.f, 0.f, 0.f);
    int e = row_start[node];
    int end = row_end[node];
    for (; e + 4 <= end; e += 4) {
        int2 r0 = csr[e];
        int2 r1 = csr[e + 1];
        int2 r2 = csr[e + 2];
        int2 r3 = csr[e + 3];
        float4 v0 = ((const float4*)(x + (size_t)r0.x * WPAD))[j];
        float4 v1 = ((const float4*)(x + (size_t)r1.x * WPAD))[j];
        float4 v2 = ((const float4*)(x + (size_t)r2.x * WPAD))[j];
        float4 v3 = ((const float4*)(x + (size_t)r3.x * WPAD))[j];
        fma4(acc, v0, __int_as_float(r0.y));
        fma4(acc, v1, __int_as_float(r1.y));
        fma4(acc, v2, __int_as_float(r2.y));
        fma4(acc, v3, __int_as_float(r3.y));
    }
    for (; e < end; ++e) {
        int2 r = csr[e];
        float4 v = ((const float4*)(x + (size_t)r.x * WPAD))[j];
        fma4(acc, v, __int_as_float(r.y));
    }
    ((float4*)rows[g])[j] = acc;
    __syncthreads();
    for (int idx = threadIdx.x; idx < GROUPS * WOUT; idx += 256) {
        int g2 = idx / WOUT;
        int j2 = idx - g2 * WOUT;
        int node2 = blockIdx.x * GROUPS + g2;
        float a = bg[j2];
#pragma unroll
        for (int k = 0; k < WIN; ++k) a += rows[g2][k] * Wg[k * WOUT + j2];
        a = lrelu(a);
        if (DBL) a = lrelu(a);
        h[(size_t)node2 * WOUT + j2] = a;
    }
}

// ---------------- Pool (batch sorted -> binary search range) ----------------
__global__ void pool_kernel(const float* __restrict__ h,
                            const int* __restrict__ batch,
                            float* __restrict__ pooled) {
    int g = blockIdx.x;
    __shared__ int s_start, s_end;
    if (threadIdx.x == 0) {
        int lo = 0, hi = N_NODES;
        while (lo < hi) { int m = (lo + hi) >> 1; if (batch[m] < g) lo = m + 1; else hi = m; }
        s_start = lo;
        lo = 0; hi = N_NODES;
        while (lo < hi) { int m = (lo + hi) >> 1; if (batch[m] < g + 1) lo = m + 1; else hi = m; }
        s_end = lo;
    }
    __syncthreads();
    int j = threadIdx.x;
    if (j < 50) {
        float acc = 0.0f;
        for (int i = s_start; i < s_end; ++i) acc += h[(size_t)i * 50 + j];
        pooled[g * 50 + j] = acc;
    }
}

// ---------------- Final MLP ----------------
__global__ void mlp_kernel(const float* __restrict__ pooled,
                           const float* __restrict__ Wf1, const float* __restrict__ bf1,
                           const float* __restrict__ Wf2, const float* __restrict__ bf2,
                           const float* __restrict__ Wf3, const float* __restrict__ bf3,
                           float* __restrict__ out) {
    __shared__ float W1s[50 * 30], b1s[30];
    __shared__ float W2s[30 * 20], b2s[20];
    __shared__ float W3s[20 * 2], b3s[2];
    for (int i = threadIdx.x; i < 50 * 30; i += blockDim.x) W1s[i] = Wf1[i];
    for (int i = threadIdx.x; i < 30; i += blockDim.x) b1s[i] = bf1[i];
    for (int i = threadIdx.x; i < 30 * 20; i += blockDim.x) W2s[i] = Wf2[i];
    for (int i = threadIdx.x; i < 20; i += blockDim.x) b2s[i] = bf2[i];
    for (int i = threadIdx.x; i < 20 * 2; i += blockDim.x) W3s[i] = Wf3[i];
    for (int i = threadIdx.x; i < 2; i += blockDim.x) b3s[i] = bf3[i];
    __syncthreads();
    int g = blockIdx.x * blockDim.x + threadIdx.x;
    if (g >= N_GRAPHS) return;
    float in[50];
#pragma unroll
    for (int k = 0; k < 50; ++k) in[k] = pooled[g * 50 + k];
    float t1[30];
#pragma unroll
    for (int j = 0; j < 30; ++j) {
        float a = b1s[j];
#pragma unroll
        for (int k = 0; k < 50; ++k) a += in[k] * W1s[k * 30 + j];
        t1[j] = lrelu(a);
    }
    float t2[20];
#pragma unroll
    for (int j = 0; j < 20; ++j) {
        float a = b2s[j];
#pragma unroll
        for (int k = 0; k < 30; ++k) a += t1[k] * W2s[k * 20 + j];
        t2[j] = lrelu(a);
    }
#pragma unroll
    for (int j = 0; j < 2; ++j) {
        float a = b3s[j];
#pragma unroll
        for (int k = 0; k < 20; ++k) a += t2[k] * W3s[k * 2 + j];
        out[g * 2 + j] = lrelu(a);
    }
}

extern "C" void kernel_launch(void* const* d_in, const int* in_sizes, int n_in,
                              void* d_out, int out_size, void* d_ws, size_t ws_size,
                              hipStream_t stream) {
    const float* x     = (const float*)d_in[0];
    const int*   ei    = (const int*)d_in[1];
    const float* ew    = (const float*)d_in[2];
    const int*   batch = (const int*)d_in[3];
    const float* W1 = (const float*)d_in[4];
    const float* b1 = (const float*)d_in[5];
    const float* W2 = (const float*)d_in[6];
    const float* b2 = (const float*)d_in[7];
    const float* W3 = (const float*)d_in[8];
    const float* b3 = (const float*)d_in[9];
    const float* W4 = (const float*)d_in[10];
    const float* b4 = (const float*)d_in[11];
    const float* Wf1 = (const float*)d_in[12];
    const float* bf1 = (const float*)d_in[13];
    const float* Wf2 = (const float*)d_in[14];
    const float* bf2 = (const float*)d_in[15];
    const float* Wf3 = (const float*)d_in[16];
    const float* bf3 = (const float*)d_in[17];

    const int* src = ei;            // edge_index[0]
    const int* dst = ei + N_EDGES;  // edge_index[1]
    float* out = (float*)d_out;

    // Workspace layout:
    //   csr        : E int2 (32 MB)
    //   bufA       : N*64 f32 (65 MB)  — staging (NB*CAP int2 = 40.6 MB) overlays
    //                                     here during CSR build, freed before L1
    //   bufB       : N*50 f32 (51 MB)  — xp [N,8] overlays the front during build
    //   row_start  : N+1 ints
    //   bucket_cnt : NB ints
    //   bucket_base: NB ints
    //   pooled     : 4096*50 f32
    char* wsp = (char*)d_ws;
    int2*  csr        = (int2*)wsp;      wsp += (size_t)N_EDGES * 8;
    float* bufA       = (float*)wsp;     wsp += (size_t)N_NODES * 64 * 4;
    float* bufB       = (float*)wsp;     wsp += (size_t)N_NODES * 50 * 4;
    int*   row_start  = (int*)wsp;       wsp += (size_t)(N_NODES + 1) * 4;
    int*   bucket_cnt = (int*)wsp;       wsp += NB * 4;
    int*   bucket_base= (int*)wsp;       wsp += NB * 4;
    float* pooled     = (float*)wsp;

    int2*  staging = (int2*)bufA;   // build-time only
    float* xp      = bufB;          // [N,8] padded x

    const int BS = 256;
    const int ABLK = (N_EDGES + EPB - 1) / EPB;   // 977

    // ---- CSR build (bucketed two-pass) + x pad ----
    hipMemsetAsync(bucket_cnt, 0, NB * 4, stream);
    pad_x_kernel<<<(N_NODES * 8 + 255) / 256, BS, 0, stream>>>(x, xp);
    partA_kernel<<<ABLK, BS, 0, stream>>>(src, dst, ew, bucket_cnt, staging);
    bucket_scan_kernel<<<1, BS, 0, stream>>>(bucket_cnt, bucket_base, row_start);
    partB_kernel<<<NB, BS, 0, stream>>>(staging, bucket_cnt, bucket_base, row_start, csr);

    // ---- 4 fused GCN layers (row_end = row_start+1: CSR is dense-ordered) ----
    gcn_layer_kernel<8, 6, 16, false><<<N_NODES / 128, BS, 0, stream>>>(
        xp, csr, row_start, row_start + 1, W1, b1, bufA);
    gcn_layer_kernel<16, 16, 32, false><<<N_NODES / 64, BS, 0, stream>>>(
        bufA, csr, row_start, row_start + 1, W2, b2, bufB);
    gcn_layer_kernel<32, 32, 64, false><<<N_NODES / 32, BS, 0, stream>>>(
        bufB, csr, row_start, row_start + 1, W3, b3, bufA);
    gcn_layer_kernel<64, 64, 50, true><<<N_NODES / 16, BS, 0, stream>>>(
        bufA, csr, row_start, row_start + 1, W4, b4, bufB);

    // ---- Pool + MLP ----
    pool_kernel<<<N_GRAPHS, 64, 0, stream>>>(bufB, batch, pooled);
    mlp_kernel<<<(N_GRAPHS + 255) / 256, 256, 0, stream>>>(pooled, Wf1, bf1, Wf2, bf2, Wf3, bf3, out);
}

// Round 5
// 759.867 us; speedup vs baseline: 3.0615x; 1.0913x over previous
//
#include <hip/hip_runtime.h>

#define N_NODES 253952   // = 992 * 256 = 248 * 1024 exactly
#define N_EDGES 4000000
#define N_GRAPHS 4096
#define NEG_SLOPE 0.01f

#define NB   248          // buckets (1024 nodes each)
#define CAP  20480        // staging capacity per bucket (mean 16129)
#define EPB  4096         // edges per partA block

__device__ __forceinline__ float lrelu(float v) {
    return v > 0.0f ? v : v * NEG_SLOPE;
}

__device__ __forceinline__ unsigned short f2bf(float f) {   // RNE
    unsigned b = __float_as_uint(f);
    return (unsigned short)((b + 0x7FFF + ((b >> 16) & 1)) >> 16);
}

__device__ __forceinline__ void fma_bf16x8(float acc[8], const uint4 v, const float w) {
    acc[0] += __uint_as_float(v.x << 16) * w;
    acc[1] += __uint_as_float(v.x & 0xFFFF0000u) * w;
    acc[2] += __uint_as_float(v.y << 16) * w;
    acc[3] += __uint_as_float(v.y & 0xFFFF0000u) * w;
    acc[4] += __uint_as_float(v.z << 16) * w;
    acc[5] += __uint_as_float(v.z & 0xFFFF0000u) * w;
    acc[6] += __uint_as_float(v.w << 16) * w;
    acc[7] += __uint_as_float(v.w & 0xFFFF0000u) * w;
}

// ---------------- CSR build, pass A: bucket partition ----------------
__global__ void partA_kernel(const int* __restrict__ src, const int* __restrict__ dst,
                             const float* __restrict__ ew,
                             int* __restrict__ bucket_cnt, int2* __restrict__ staging) {
    __shared__ int cnt[NB], base[NB], cur[NB];
    for (int i = threadIdx.x; i < NB; i += 256) cnt[i] = 0;
    __syncthreads();
    const int e0 = blockIdx.x * EPB;
    int s[16], d[16]; float w[16];
#pragma unroll
    for (int k = 0; k < 16; ++k) {
        int e = e0 + k * 256 + threadIdx.x;
        if (e < N_EDGES) { s[k] = src[e]; d[k] = dst[e]; w[k] = ew[e]; }
        else d[k] = -1;
    }
#pragma unroll
    for (int k = 0; k < 16; ++k)
        if (d[k] >= 0) atomicAdd(&cnt[d[k] >> 10], 1);
    __syncthreads();
    for (int i = threadIdx.x; i < NB; i += 256) {
        int c = cnt[i];
        base[i] = (c > 0) ? atomicAdd(&bucket_cnt[i], c) : 0;
        cur[i] = 0;
    }
    __syncthreads();
#pragma unroll
    for (int k = 0; k < 16; ++k) {
        if (d[k] >= 0) {
            int b = d[k] >> 10;
            int off = atomicAdd(&cur[b], 1);
            staging[(size_t)b * CAP + base[b] + off] =
                make_int2(s[k] | ((d[k] & 1023) << 18), __float_as_int(w[k]));
        }
    }
}

__global__ void bucket_scan_kernel(const int* __restrict__ bucket_cnt,
                                   int* __restrict__ bucket_base,
                                   int* __restrict__ row_start) {
    __shared__ int s[256];
    int v = (threadIdx.x < NB) ? bucket_cnt[threadIdx.x] : 0;
    s[threadIdx.x] = v;
    __syncthreads();
    for (int off = 1; off < 256; off <<= 1) {
        int t = (threadIdx.x >= off) ? s[threadIdx.x - off] : 0;
        __syncthreads();
        s[threadIdx.x] += t;
        __syncthreads();
    }
    if (threadIdx.x < NB) bucket_base[threadIdx.x] = s[threadIdx.x] - v;
    if (threadIdx.x == 0) row_start[N_NODES] = N_EDGES;   // sentinel
}

// ---------------- CSR build, pass B: per-bucket counting sort ----------------
__global__ void partB_kernel(const int2* __restrict__ staging,
                             const int* __restrict__ bucket_cnt,
                             const int* __restrict__ bucket_base,
                             int* __restrict__ row_start, int2* __restrict__ csr) {
    __shared__ int hist[1024];
    __shared__ int scan_s[256];
    const int b = blockIdx.x;
    const int cnt = bucket_cnt[b];
    const int bbase = bucket_base[b];
    const int2* rec = staging + (size_t)b * CAP;
    for (int i = threadIdx.x; i < 1024; i += 256) hist[i] = 0;
    __syncthreads();
    for (int i = threadIdx.x; i < cnt; i += 256)
        atomicAdd(&hist[rec[i].x >> 18], 1);
    __syncthreads();
    const int t = threadIdx.x;
    int h0 = hist[4 * t], h1 = hist[4 * t + 1], h2 = hist[4 * t + 2], h3 = hist[4 * t + 3];
    int sum = h0 + h1 + h2 + h3;
    scan_s[t] = sum;
    __syncthreads();
    for (int off = 1; off < 256; off <<= 1) {
        int tv = (t >= off) ? scan_s[t - off] : 0;
        __syncthreads();
        scan_s[t] += tv;
        __syncthreads();
    }
    int excl = scan_s[t] - sum;
    int e0 = excl, e1 = excl + h0, e2 = excl + h0 + h1, e3 = excl + h0 + h1 + h2;
    int node0 = b * 1024 + 4 * t;
    row_start[node0]     = bbase + e0;
    row_start[node0 + 1] = bbase + e1;
    row_start[node0 + 2] = bbase + e2;
    row_start[node0 + 3] = bbase + e3;
    hist[4 * t] = e0; hist[4 * t + 1] = e1; hist[4 * t + 2] = e2; hist[4 * t + 3] = e3;
    __syncthreads();
    for (int i = threadIdx.x; i < cnt; i += 256) {
        int2 r = rec[i];
        int dl = r.x >> 18;
        int pos = bbase + atomicAdd(&hist[dl], 1);
        csr[pos] = make_int2(r.x & 0x3FFFF, r.y);
    }
}

// Pad + convert x [N,6] f32 -> xb [N,8] bf16 (zeros in 6,7).
__global__ void pad_x_kernel(const float* __restrict__ x, unsigned short* __restrict__ xb) {
    int i = blockIdx.x * 256 + threadIdx.x;
    if (i >= N_NODES * 8) return;
    int n = i >> 3, j = i & 7;
    xb[i] = (j < 6) ? f2bf(x[n * 6 + j]) : (unsigned short)0;
}

// ---------------- Fused GCN layer: bf16 CSR gather + linear + lrelu ----------
// WPAD: bf16 input row width (mult of 8). LPN = WPAD/8 lanes/node, each lane
// gathers one uint4 (8 bf16) per edge; accumulate fp32; LDS; WIN->WOUT GEMM.
template <int WPAD, int WIN, int WOUT, bool DBL, bool OUT_F32>
__global__ void gcn_layer_kernel(const unsigned short* __restrict__ xb, const int2* __restrict__ csr,
                                 const int* __restrict__ row_start, const int* __restrict__ row_end,
                                 const float* __restrict__ Wg, const float* __restrict__ bg,
                                 void* __restrict__ hout) {
    constexpr int LPN = WPAD / 8;
    constexpr int GROUPS = 256 / LPN;
    __shared__ float rows[GROUPS][WPAD + 4];   // +4: break 32-bank stride
    int g = threadIdx.x / LPN;
    int j = threadIdx.x % LPN;
    int node = blockIdx.x * GROUPS + g;   // N_NODES % GROUPS == 0
    float acc[8] = {0.f, 0.f, 0.f, 0.f, 0.f, 0.f, 0.f, 0.f};
    int e = row_start[node];
    int end = row_end[node];
    for (; e + 4 <= end; e += 4) {
        int2 r0 = csr[e];
        int2 r1 = csr[e + 1];
        int2 r2 = csr[e + 2];
        int2 r3 = csr[e + 3];
        uint4 v0 = ((const uint4*)(xb + (size_t)r0.x * WPAD))[j];
        uint4 v1 = ((const uint4*)(xb + (size_t)r1.x * WPAD))[j];
        uint4 v2 = ((const uint4*)(xb + (size_t)r2.x * WPAD))[j];
        uint4 v3 = ((const uint4*)(xb + (size_t)r3.x * WPAD))[j];
        fma_bf16x8(acc, v0, __int_as_float(r0.y));
        fma_bf16x8(acc, v1, __int_as_float(r1.y));
        fma_bf16x8(acc, v2, __int_as_float(r2.y));
        fma_bf16x8(acc, v3, __int_as_float(r3.y));
    }
    for (; e < end; ++e) {
        int2 r = csr[e];
        uint4 v = ((const uint4*)(xb + (size_t)r.x * WPAD))[j];
        fma_bf16x8(acc, v, __int_as_float(r.y));
    }
#pragma unroll
    for (int i = 0; i < 8; ++i) rows[g][8 * j + i] = acc[i];
    __syncthreads();
    for (int idx = threadIdx.x; idx < GROUPS * WOUT; idx += 256) {
        int g2 = idx / WOUT;
        int j2 = idx - g2 * WOUT;
        int node2 = blockIdx.x * GROUPS + g2;
        float a = bg[j2];
#pragma unroll
        for (int k = 0; k < WIN; ++k) a += rows[g2][k] * Wg[k * WOUT + j2];
        a = lrelu(a);
        if (DBL) a = lrelu(a);
        if (OUT_F32) ((float*)hout)[(size_t)node2 * WOUT + j2] = a;
        else ((unsigned short*)hout)[(size_t)node2 * WOUT + j2] = f2bf(a);
    }
}

// ---------------- Pool (batch sorted -> binary search range) ----------------
__global__ void pool_kernel(const float* __restrict__ h,
                            const int* __restrict__ batch,
                            float* __restrict__ pooled) {
    int g = blockIdx.x;
    __shared__ int s_start, s_end;
    if (threadIdx.x == 0) {
        int lo = 0, hi = N_NODES;
        while (lo < hi) { int m = (lo + hi) >> 1; if (batch[m] < g) lo = m + 1; else hi = m; }
        s_start = lo;
        lo = 0; hi = N_NODES;
        while (lo < hi) { int m = (lo + hi) >> 1; if (batch[m] < g + 1) lo = m + 1; else hi = m; }
        s_end = lo;
    }
    __syncthreads();
    int j = threadIdx.x;
    if (j < 50) {
        float acc = 0.0f;
        for (int i = s_start; i < s_end; ++i) acc += h[(size_t)i * 50 + j];
        pooled[g * 50 + j] = acc;
    }
}

// ---------------- Final MLP ----------------
__global__ void mlp_kernel(const float* __restrict__ pooled,
                           const float* __restrict__ Wf1, const float* __restrict__ bf1,
                           const float* __restrict__ Wf2, const float* __restrict__ bf2,
                           const float* __restrict__ Wf3, const float* __restrict__ bf3,
                           float* __restrict__ out) {
    __shared__ float W1s[50 * 30], b1s[30];
    __shared__ float W2s[30 * 20], b2s[20];
    __shared__ float W3s[20 * 2], b3s[2];
    for (int i = threadIdx.x; i < 50 * 30; i += blockDim.x) W1s[i] = Wf1[i];
    for (int i = threadIdx.x; i < 30; i += blockDim.x) b1s[i] = bf1[i];
    for (int i = threadIdx.x; i < 30 * 20; i += blockDim.x) W2s[i] = Wf2[i];
    for (int i = threadIdx.x; i < 20; i += blockDim.x) b2s[i] = bf2[i];
    for (int i = threadIdx.x; i < 20 * 2; i += blockDim.x) W3s[i] = Wf3[i];
    for (int i = threadIdx.x; i < 2; i += blockDim.x) b3s[i] = bf3[i];
    __syncthreads();
    int g = blockIdx.x * blockDim.x + threadIdx.x;
    if (g >= N_GRAPHS) return;
    float in[50];
#pragma unroll
    for (int k = 0; k < 50; ++k) in[k] = pooled[g * 50 + k];
    float t1[30];
#pragma unroll
    for (int j = 0; j < 30; ++j) {
        float a = b1s[j];
#pragma unroll
        for (int k = 0; k < 50; ++k) a += in[k] * W1s[k * 30 + j];
        t1[j] = lrelu(a);
    }
    float t2[20];
#pragma unroll
    for (int j = 0; j < 20; ++j) {
        float a = b2s[j];
#pragma unroll
        for (int k = 0; k < 30; ++k) a += t1[k] * W2s[k * 20 + j];
        t2[j] = lrelu(a);
    }
#pragma unroll
    for (int j = 0; j < 2; ++j) {
        float a = b3s[j];
#pragma unroll
        for (int k = 0; k < 20; ++k) a += t2[k] * W3s[k * 2 + j];
        out[g * 2 + j] = lrelu(a);
    }
}

extern "C" void kernel_launch(void* const* d_in, const int* in_sizes, int n_in,
                              void* d_out, int out_size, void* d_ws, size_t ws_size,
                              hipStream_t stream) {
    const float* x     = (const float*)d_in[0];
    const int*   ei    = (const int*)d_in[1];
    const float* ew    = (const float*)d_in[2];
    const int*   batch = (const int*)d_in[3];
    const float* W1 = (const float*)d_in[4];
    const float* b1 = (const float*)d_in[5];
    const float* W2 = (const float*)d_in[6];
    const float* b2 = (const float*)d_in[7];
    const float* W3 = (const float*)d_in[8];
    const float* b3 = (const float*)d_in[9];
    const float* W4 = (const float*)d_in[10];
    const float* b4 = (const float*)d_in[11];
    const float* Wf1 = (const float*)d_in[12];
    const float* bf1 = (const float*)d_in[13];
    const float* Wf2 = (const float*)d_in[14];
    const float* bf2 = (const float*)d_in[15];
    const float* Wf3 = (const float*)d_in[16];
    const float* bf3 = (const float*)d_in[17];

    const int* src = ei;            // edge_index[0]
    const int* dst = ei + N_EDGES;  // edge_index[1]
    float* out = (float*)d_out;

    // Workspace (byte sizes kept generous; bf16 buffers reuse fp32-sized slots):
    //   csr        : E int2 (32 MB)
    //   bufA       : N*64*4 B — staging (NB*CAP int2 = 40.6 MB) overlays during build,
    //                then h1 [N,16]bf16 / h3 [N,64]bf16
    //   bufB       : N*50*4 B — xb [N,8]bf16 at front during build/L1,
    //                then h2 [N,32]bf16, then h4 [N,50]f32
    //   row_start  : N+1 ints
    //   bucket_cnt/base : NB ints each
    //   pooled     : 4096*50 f32
    char* wsp = (char*)d_ws;
    int2*  csr        = (int2*)wsp;      wsp += (size_t)N_EDGES * 8;
    char*  bufA       = wsp;             wsp += (size_t)N_NODES * 64 * 4;
    char*  bufB       = wsp;             wsp += (size_t)N_NODES * 50 * 4;
    int*   row_start  = (int*)wsp;       wsp += (size_t)(N_NODES + 1) * 4;
    int*   bucket_cnt = (int*)wsp;       wsp += NB * 4;
    int*   bucket_base= (int*)wsp;       wsp += NB * 4;
    float* pooled     = (float*)wsp;

    int2*           staging = (int2*)bufA;            // build-time only
    unsigned short* xb      = (unsigned short*)bufB;  // [N,8] bf16
    unsigned short* h1      = (unsigned short*)bufA;  // [N,16]
    unsigned short* h2      = (unsigned short*)(bufB + (size_t)N_NODES * 8 * 2); // [N,32], after xb
    unsigned short* h3      = (unsigned short*)bufA;  // [N,64]
    float*          h4      = (float*)bufB;           // [N,50] f32 (xb/h2 dead by then)

    const int BS = 256;
    const int ABLK = (N_EDGES + EPB - 1) / EPB;   // 977

    // ---- CSR build (bucketed two-pass) + x pad/convert ----
    hipMemsetAsync(bucket_cnt, 0, NB * 4, stream);
    pad_x_kernel<<<(N_NODES * 8 + 255) / 256, BS, 0, stream>>>(x, xb);
    partA_kernel<<<ABLK, BS, 0, stream>>>(src, dst, ew, bucket_cnt, staging);
    bucket_scan_kernel<<<1, BS, 0, stream>>>(bucket_cnt, bucket_base, row_start);
    partB_kernel<<<NB, BS, 0, stream>>>(staging, bucket_cnt, bucket_base, row_start, csr);

    // ---- 4 fused GCN layers (bf16 features, fp32 accumulate) ----
    gcn_layer_kernel<8, 6, 16, false, false><<<N_NODES / 256, BS, 0, stream>>>(
        xb, csr, row_start, row_start + 1, W1, b1, h1);
    gcn_layer_kernel<16, 16, 32, false, false><<<N_NODES / 128, BS, 0, stream>>>(
        h1, csr, row_start, row_start + 1, W2, b2, h2);
    gcn_layer_kernel<32, 32, 64, false, false><<<N_NODES / 64, BS, 0, stream>>>(
        h2, csr, row_start, row_start + 1, W3, b3, h3);
    gcn_layer_kernel<64, 64, 50, true, true><<<N_NODES / 32, BS, 0, stream>>>(
        h3, csr, row_start, row_start + 1, W4, b4, h4);

    // ---- Pool + MLP ----
    pool_kernel<<<N_GRAPHS, 64, 0, stream>>>(h4, batch, pooled);
    mlp_kernel<<<(N_GRAPHS + 255) / 256, 256, 0, stream>>>(pooled, Wf1, bf1, Wf2, bf2, Wf3, bf3, out);
}